// Round 7
// baseline (138.700 us; speedup 1.0000x reference)
//
#include <hip/hip_runtime.h>
#include <hip/hip_bf16.h>
#include <math.h>

typedef __attribute__((ext_vector_type(8))) short bf16x8;
typedef __attribute__((ext_vector_type(4))) float f32x4;

__device__ __forceinline__ unsigned f2bfu(float f) {
    __hip_bfloat16 b = __float2bfloat16(f);
    return (unsigned)*reinterpret_cast<unsigned short*>(&b);
}

__device__ __forceinline__ bf16x8 cvt8(float4 a, float4 b) {
    bf16x8 r;
    r[0] = (short)f2bfu(a.x); r[1] = (short)f2bfu(a.y);
    r[2] = (short)f2bfu(a.z); r[3] = (short)f2bfu(a.w);
    r[4] = (short)f2bfu(b.x); r[5] = (short)f2bfu(b.y);
    r[6] = (short)f2bfu(b.z); r[7] = (short)f2bfu(b.w);
    return r;
}

// ===========================================================================
// prep kernel: [0,128) L0 proj, [128,160) L1 proj, [160,168) L2 proj,
// [168,268) offsets GEMM (MFMA bf16), [268] W_out transpose.
// proj: P[h][pix][16] = Wk_head_h(16xC) @ feat(Cx128pix), per-head layout.
// ===========================================================================
template<int C>
__device__ __forceinline__ void proj_mfma(
    unsigned short* lds, const float* __restrict__ feat,
    const float* __restrict__ Wk, __hip_bfloat16* __restrict__ P,
    int HW, int pblk)
{
    constexpr int GR = C / 8;    // 16B granules per pixel row
    constexpr int KK = C / 32;   // mfma chain length over K
    const int tid = threadIdx.x;
    const int p0 = pblk * 128;

    // stage feat tile -> bf16 LDS [pix][C], granule-XOR swizzle (by pix)
    for (int u = tid; u < (C / 2) * 32; u += 256) {
        int cip = u >> 5;
        int p4 = (u & 31) << 2;
        int ci = cip << 1;
        float4 lo = *reinterpret_cast<const float4*>(feat + (size_t)ci * HW + p0 + p4);
        float4 hi = *reinterpret_cast<const float4*>(feat + (size_t)(ci + 1) * HW + p0 + p4);
        float lov[4] = {lo.x, lo.y, lo.z, lo.w};
        float hiv[4] = {hi.x, hi.y, hi.z, hi.w};
        int g = ci >> 3;
        #pragma unroll
        for (int j = 0; j < 4; ++j) {
            int pix = p4 + j;
            int gs = g ^ (pix & (GR - 1));
            unsigned pack = f2bfu(lov[j]) | (f2bfu(hiv[j]) << 16);
            *reinterpret_cast<unsigned*>(lds + pix * C + gs * 8 + (ci & 7)) = pack;
        }
    }
    __syncthreads();

    const int wave = tid >> 6, lane = tid & 63;
    const int col = lane & 15, g4 = lane >> 4;

    bf16x8 bfrag[2][KK];
    #pragma unroll
    for (int st = 0; st < 2; ++st) {
        int pix = (wave * 2 + st) * 16 + col;
        #pragma unroll
        for (int kk = 0; kk < KK; ++kk) {
            int gs = (kk * 4 + g4) ^ (pix & (GR - 1));
            bfrag[st][kk] = *reinterpret_cast<const bf16x8*>(lds + pix * C + gs * 8);
        }
    }
    #pragma unroll
    for (int h = 0; h < 8; ++h) {
        bf16x8 afrag[KK];
        #pragma unroll
        for (int kk = 0; kk < KK; ++kk) {
            const float* wp = Wk + (size_t)(h * 16 + col) * C + kk * 32 + g4 * 8;
            afrag[kk] = cvt8(*reinterpret_cast<const float4*>(wp),
                             *reinterpret_cast<const float4*>(wp + 4));
        }
        #pragma unroll
        for (int st = 0; st < 2; ++st) {
            f32x4 acc = {0.f, 0.f, 0.f, 0.f};
            #pragma unroll
            for (int kk = 0; kk < KK; ++kk)
                acc = __builtin_amdgcn_mfma_f32_16x16x32_bf16(afrag[kk], bfrag[st][kk], acc, 0, 0, 0);
            int pix = p0 + (wave * 2 + st) * 16 + col;
            unsigned lo = f2bfu(acc[0]) | (f2bfu(acc[1]) << 16);
            unsigned hi = f2bfu(acc[2]) | (f2bfu(acc[3]) << 16);
            uint2 od = make_uint2(lo, hi);
            *reinterpret_cast<uint2*>(reinterpret_cast<char*>(P) +
                (size_t)(h * HW + pix) * 32 + g4 * 8) = od;
        }
    }
}

__device__ __forceinline__ void off_mfma(
    const float* __restrict__ query, const float* __restrict__ W_off,
    const float* __restrict__ b_off, float* __restrict__ offv, int qblk)
{
    const int tid = threadIdx.x;
    const int wave = tid >> 6, lane = tid & 63;
    const int col = lane & 15, g4 = lane >> 4;
    const int q = qblk * 64 + wave * 16 + col;

    bf16x8 bfrag[4];
    #pragma unroll
    for (int kk = 0; kk < 4; ++kk) {
        const float* qp = query + (size_t)q * 128 + kk * 32 + g4 * 8;
        bfrag[kk] = cvt8(*reinterpret_cast<const float4*>(qp),
                         *reinterpret_cast<const float4*>(qp + 4));
    }
    #pragma unroll
    for (int mt = 0; mt < 12; ++mt) {
        bf16x8 afrag[4];
        #pragma unroll
        for (int kk = 0; kk < 4; ++kk) {
            const float* wp = W_off + (size_t)(mt * 16 + col) * 128 + kk * 32 + g4 * 8;
            afrag[kk] = cvt8(*reinterpret_cast<const float4*>(wp),
                             *reinterpret_cast<const float4*>(wp + 4));
        }
        f32x4 acc = {0.f, 0.f, 0.f, 0.f};
        #pragma unroll
        for (int kk = 0; kk < 4; ++kk)
            acc = __builtin_amdgcn_mfma_f32_16x16x32_bf16(afrag[kk], bfrag[kk], acc, 0, 0, 0);
        float4 bias = *reinterpret_cast<const float4*>(b_off + mt * 16 + g4 * 4);
        float4 o = make_float4(acc[0] + bias.x, acc[1] + bias.y,
                               acc[2] + bias.z, acc[3] + bias.w);
        *reinterpret_cast<float4*>(offv + (size_t)q * 192 + mt * 16 + g4 * 4) = o;
    }
}

__global__ __launch_bounds__(256) void prep4_kernel(
    const float* __restrict__ feat0, const float* __restrict__ feat1,
    const float* __restrict__ feat2,
    const float* __restrict__ Wk0, const float* __restrict__ Wk1,
    const float* __restrict__ Wk2,
    __hip_bfloat16* __restrict__ P0, __hip_bfloat16* __restrict__ P1,
    __hip_bfloat16* __restrict__ P2,
    const float* __restrict__ query, const float* __restrict__ W_off,
    const float* __restrict__ b_off, float* __restrict__ offv,
    const float* __restrict__ W_out, float* __restrict__ WT)
{
    __shared__ __align__(16) unsigned short lds[128 * 128];  // 32 KB
    int b = blockIdx.x;
    if (b < 128)      proj_mfma<128>(lds, feat0, Wk0, P0, 16384, b);
    else if (b < 160) proj_mfma<128>(lds, feat1, Wk1, P1, 4096, b - 128);
    else if (b < 168) proj_mfma<64>(lds, feat2, Wk2, P2, 1024, b - 160);
    else if (b < 268) off_mfma(query, W_off, b_off, offv, b - 168);
    else {
        // transpose W_out (128x128) -> WT[ci][co]
        for (int idx = threadIdx.x; idx < 128 * 128; idx += 256) {
            int co = idx >> 7, ci = idx & 127;
            WT[ci * 128 + co] = W_out[co * 128 + ci];
        }
    }
}

// ===========================================================================
// attn5: 256 threads, 2 queries per block (3200 blocks). Per query:
// geometry precompute (96 samples) -> 4-lane-per-sample gather (uint2
// corners, bilinear in-reg, shfl logit reduce) -> softmax+combine ->
// fused output projection via pre-transposed W_out (coalesced GEMV).
// ===========================================================================
__global__ __launch_bounds__(256) void attn5_kernel(
    const float* __restrict__ query, const float* __restrict__ ref,
    const float* __restrict__ offv,
    const __hip_bfloat16* __restrict__ P0, const __hip_bfloat16* __restrict__ P1,
    const __hip_bfloat16* __restrict__ P2,
    const float* __restrict__ bk0, const float* __restrict__ bk1,
    const float* __restrict__ bk2,
    const float* __restrict__ WT, const float* __restrict__ b_out,
    float* __restrict__ out)
{
    __shared__ __align__(16) float q_sh[2][128];
    __shared__ __align__(16) float bias_sh[3][128];
    __shared__ float logit_sh[2][96];
    __shared__ __align__(16) float k_sh[2][96 * 20];
    __shared__ __align__(16) unsigned gaddr[2][96][4];
    __shared__ __align__(16) float gw[2][96][4];
    __shared__ __align__(16) float h_sh[2][128];
    const int q0 = blockIdx.x * 2;
    const int tid = threadIdx.x;
    const int qloc = tid >> 7;
    const int t = tid & 127;

    q_sh[qloc][t] = query[(q0 + qloc) * 128 + t];
    if (tid < 128) {
        bias_sh[0][t] = bk0[t];
        bias_sh[1][t] = bk1[t];
        bias_sh[2][t] = bk2[t];
    }
    if (tid < 192) {
        int qg = tid / 96;
        int s = tid - qg * 96;
        int qq = q0 + qg;
        int h = (s * 171) >> 11;       // s/12
        int lp = s - h * 12;
        int l = lp >> 2;
        int W = 128 >> l;
        float ox = offv[qq * 192 + 2 * s];
        float oy = offv[qq * 192 + 2 * s + 1];
        float x = fmaf(ref[qq * 6 + 2 * l], (float)W, ox) - 0.5f;
        float y = fmaf(ref[qq * 6 + 2 * l + 1], (float)W, oy) - 0.5f;
        float x0f = floorf(x), y0f = floorf(y);
        float wx = x - x0f, wy = y - y0f;
        int x0 = (int)x0f, y0 = (int)y0f;
        int x1 = x0 + 1, y1 = y0 + 1;
        float mx0 = (x0 >= 0 && x0 < W) ? 1.f : 0.f;
        float mx1 = (x1 >= 0 && x1 < W) ? 1.f : 0.f;
        float my0 = (y0 >= 0 && y0 < W) ? 1.f : 0.f;
        float my1 = (y1 >= 0 && y1 < W) ? 1.f : 0.f;
        int xc0 = min(max(x0, 0), W - 1), xc1 = min(max(x1, 0), W - 1);
        int yc0 = min(max(y0, 0), W - 1), yc1 = min(max(y1, 0), W - 1);
        unsigned pb = (unsigned)(h * W * W) * 32u;
        gaddr[qg][s][0] = pb + (unsigned)(yc0 * W + xc0) * 32u;
        gaddr[qg][s][1] = pb + (unsigned)(yc0 * W + xc1) * 32u;
        gaddr[qg][s][2] = pb + (unsigned)(yc1 * W + xc0) * 32u;
        gaddr[qg][s][3] = pb + (unsigned)(yc1 * W + xc1) * 32u;
        gw[qg][s][0] = (1.f - wx) * (1.f - wy) * mx0 * my0;
        gw[qg][s][1] = wx * (1.f - wy) * mx1 * my0;
        gw[qg][s][2] = (1.f - wx) * wy * mx0 * my1;
        gw[qg][s][3] = wx * wy * mx1 * my1;
    }
    __syncthreads();

    // gather: 2q x 96s x 4 lanes = 768 lane-samples over 3 iterations
    const int quad = tid & 3;
    uint2 raw[3][4];
    float4 wv[3];
    #pragma unroll
    for (int it = 0; it < 3; ++it) {
        int sg = it * 64 + (tid >> 2);       // 0..191
        int qg = (sg >= 96) ? 1 : 0;
        int s = sg - qg * 96;
        int h = (s * 171) >> 11;
        int lp = s - h * 12;
        int l = lp >> 2;
        uint4 av = *reinterpret_cast<const uint4*>(&gaddr[qg][s][0]);
        wv[it] = *reinterpret_cast<const float4*>(&gw[qg][s][0]);
        const char* base = ((l == 0) ? (const char*)P0 :
                            (l == 1) ? (const char*)P1 : (const char*)P2) + quad * 8;
        raw[it][0] = *reinterpret_cast<const uint2*>(base + av.x);
        raw[it][1] = *reinterpret_cast<const uint2*>(base + av.y);
        raw[it][2] = *reinterpret_cast<const uint2*>(base + av.z);
        raw[it][3] = *reinterpret_cast<const uint2*>(base + av.w);
    }
    #pragma unroll
    for (int it = 0; it < 3; ++it) {
        int sg = it * 64 + (tid >> 2);
        int qg = (sg >= 96) ? 1 : 0;
        int s = sg - qg * 96;
        int h = (s * 171) >> 11;
        int lp = s - h * 12;
        int l = lp >> 2;
        float k0 = 0.f, k1 = 0.f, k2 = 0.f, k3 = 0.f;
        float wc[4] = {wv[it].x, wv[it].y, wv[it].z, wv[it].w};
        #pragma unroll
        for (int cnr = 0; cnr < 4; ++cnr) {
            unsigned a = raw[it][cnr].x, b2 = raw[it][cnr].y;
            float w = wc[cnr];
            k0 = fmaf(w, __uint_as_float(a << 16), k0);
            k1 = fmaf(w, __uint_as_float(a & 0xffff0000u), k1);
            k2 = fmaf(w, __uint_as_float(b2 << 16), k2);
            k3 = fmaf(w, __uint_as_float(b2 & 0xffff0000u), k3);
        }
        int co = h * 16 + quad * 4;
        float4 bias = *reinterpret_cast<const float4*>(&bias_sh[l][co]);
        k0 += bias.x; k1 += bias.y; k2 += bias.z; k3 += bias.w;
        float4 qv = *reinterpret_cast<const float4*>(&q_sh[qg][co]);
        float lg = k0 * qv.x;
        lg = fmaf(k1, qv.y, lg);
        lg = fmaf(k2, qv.z, lg);
        lg = fmaf(k3, qv.w, lg);
        lg += __shfl_xor(lg, 1);
        lg += __shfl_xor(lg, 2);
        *reinterpret_cast<float4*>(&k_sh[qg][s * 20 + quad * 4]) = make_float4(k0, k1, k2, k3);
        if (quad == 0) logit_sh[qg][s] = lg;
    }
    __syncthreads();

    // softmax + combine: tid -> (qg, h, d)
    {
        int qg = tid >> 7;
        int h2 = (tid >> 4) & 7;
        int dd = tid & 15;
        float m = -1e30f;
        #pragma unroll
        for (int j = 0; j < 12; ++j) m = fmaxf(m, logit_sh[qg][h2 * 12 + j]);
        float ssum = 0.f, o = 0.f;
        #pragma unroll
        for (int j = 0; j < 12; ++j) {
            float e = __expf(0.25f * (logit_sh[qg][h2 * 12 + j] - m));
            ssum += e;
            o = fmaf(e, k_sh[qg][(h2 * 12 + j) * 20 + dd], o);
        }
        h_sh[qg][h2 * 16 + dd] = o / ssum;
    }
    __syncthreads();

    // fused output projection: thread (c=t, qh=qloc): out = WT[:,c].h + b
    {
        const float* wt = WT + t;
        float acc = 0.f;
        #pragma unroll 8
        for (int k = 0; k < 128; k += 4) {
            float4 h4 = *reinterpret_cast<const float4*>(&h_sh[qloc][k]);
            acc = fmaf(wt[(k + 0) * 128], h4.x, acc);
            acc = fmaf(wt[(k + 1) * 128], h4.y, acc);
            acc = fmaf(wt[(k + 2) * 128], h4.z, acc);
            acc = fmaf(wt[(k + 3) * 128], h4.w, acc);
        }
        out[(q0 + qloc) * 128 + t] = acc + b_out[t];
    }
}

// ===========================================================================
extern "C" void kernel_launch(void* const* d_in, const int* in_sizes, int n_in,
                              void* d_out, int out_size, void* d_ws, size_t ws_size,
                              hipStream_t stream) {
    const float* query = (const float*)d_in[0];
    const float* ref   = (const float*)d_in[1];
    const float* feat0 = (const float*)d_in[2];
    const float* feat1 = (const float*)d_in[3];
    const float* feat2 = (const float*)d_in[4];
    const float* W_off = (const float*)d_in[6];
    const float* b_off = (const float*)d_in[7];
    const float* Wk0   = (const float*)d_in[8];
    const float* bk0   = (const float*)d_in[9];
    const float* Wk1   = (const float*)d_in[10];
    const float* bk1   = (const float*)d_in[11];
    const float* Wk2   = (const float*)d_in[12];
    const float* bk2   = (const float*)d_in[13];
    const float* W_out = (const float*)d_in[14];
    const float* b_out = (const float*)d_in[15];
    float* out = (float*)d_out;

    __hip_bfloat16* P0 = (__hip_bfloat16*)d_ws;     // [8][16384][16] bf16
    __hip_bfloat16* P1 = P0 + 8 * 16384 * 16;       // [8][4096][16]
    __hip_bfloat16* P2 = P1 + 8 * 4096 * 16;        // [8][1024][16]
    float* offv = (float*)(P2 + 8 * 1024 * 16);     // [6400][192] f32
    float* WT   = offv + 6400 * 192;                // [128][128] f32 transposed W_out

    hipLaunchKernelGGL(prep4_kernel, dim3(269), dim3(256), 0, stream,
                       feat0, feat1, feat2, Wk0, Wk1, Wk2, P0, P1, P2,
                       query, W_off, b_off, offv, W_out, WT);
    hipLaunchKernelGGL(attn5_kernel, dim3(3200), dim3(256), 0, stream,
                       query, ref, offv, P0, P1, P2, bk0, bk1, bk2,
                       WT, b_out, out);
}

// Round 8
// 132.510 us; speedup vs baseline: 1.0467x; 1.0467x over previous
//
#include <hip/hip_runtime.h>
#include <hip/hip_bf16.h>
#include <math.h>

typedef __attribute__((ext_vector_type(8))) short bf16x8;
typedef __attribute__((ext_vector_type(4))) float f32x4;

__device__ __forceinline__ unsigned f2bfu(float f) {
    __hip_bfloat16 b = __float2bfloat16(f);
    return (unsigned)*reinterpret_cast<unsigned short*>(&b);
}

__device__ __forceinline__ bf16x8 cvt8(float4 a, float4 b) {
    bf16x8 r;
    r[0] = (short)f2bfu(a.x); r[1] = (short)f2bfu(a.y);
    r[2] = (short)f2bfu(a.z); r[3] = (short)f2bfu(a.w);
    r[4] = (short)f2bfu(b.x); r[5] = (short)f2bfu(b.y);
    r[6] = (short)f2bfu(b.z); r[7] = (short)f2bfu(b.w);
    return r;
}

// ===========================================================================
// prep kernel: [0,128) L0 proj, [128,160) L1 proj, [160,168) L2 proj,
// [168,268) offsets GEMM. MFMA bf16 throughout.
// proj: P[h][pix][16] = Wk_head_h(16xC) @ feat(Cx128pix), per-head layout.
// ===========================================================================
template<int C>
__device__ __forceinline__ void proj_mfma(
    unsigned short* lds, const float* __restrict__ feat,
    const float* __restrict__ Wk, __hip_bfloat16* __restrict__ P,
    int HW, int pblk)
{
    constexpr int GR = C / 8;    // 16B granules per pixel row
    constexpr int KK = C / 32;   // mfma chain length over K
    const int tid = threadIdx.x;
    const int p0 = pblk * 128;

    // stage feat tile -> bf16 LDS [pix][C], granule-XOR swizzle (by pix)
    for (int u = tid; u < (C / 2) * 32; u += 256) {
        int cip = u >> 5;
        int p4 = (u & 31) << 2;
        int ci = cip << 1;
        float4 lo = *reinterpret_cast<const float4*>(feat + (size_t)ci * HW + p0 + p4);
        float4 hi = *reinterpret_cast<const float4*>(feat + (size_t)(ci + 1) * HW + p0 + p4);
        float lov[4] = {lo.x, lo.y, lo.z, lo.w};
        float hiv[4] = {hi.x, hi.y, hi.z, hi.w};
        int g = ci >> 3;
        #pragma unroll
        for (int j = 0; j < 4; ++j) {
            int pix = p4 + j;
            int gs = g ^ (pix & (GR - 1));
            unsigned pack = f2bfu(lov[j]) | (f2bfu(hiv[j]) << 16);
            *reinterpret_cast<unsigned*>(lds + pix * C + gs * 8 + (ci & 7)) = pack;
        }
    }
    __syncthreads();

    const int wave = tid >> 6, lane = tid & 63;
    const int col = lane & 15, g4 = lane >> 4;

    bf16x8 bfrag[2][KK];
    #pragma unroll
    for (int st = 0; st < 2; ++st) {
        int pix = (wave * 2 + st) * 16 + col;
        #pragma unroll
        for (int kk = 0; kk < KK; ++kk) {
            int gs = (kk * 4 + g4) ^ (pix & (GR - 1));
            bfrag[st][kk] = *reinterpret_cast<const bf16x8*>(lds + pix * C + gs * 8);
        }
    }
    #pragma unroll
    for (int h = 0; h < 8; ++h) {
        bf16x8 afrag[KK];
        #pragma unroll
        for (int kk = 0; kk < KK; ++kk) {
            const float* wp = Wk + (size_t)(h * 16 + col) * C + kk * 32 + g4 * 8;
            afrag[kk] = cvt8(*reinterpret_cast<const float4*>(wp),
                             *reinterpret_cast<const float4*>(wp + 4));
        }
        #pragma unroll
        for (int st = 0; st < 2; ++st) {
            f32x4 acc = {0.f, 0.f, 0.f, 0.f};
            #pragma unroll
            for (int kk = 0; kk < KK; ++kk)
                acc = __builtin_amdgcn_mfma_f32_16x16x32_bf16(afrag[kk], bfrag[st][kk], acc, 0, 0, 0);
            int pix = p0 + (wave * 2 + st) * 16 + col;
            unsigned lo = f2bfu(acc[0]) | (f2bfu(acc[1]) << 16);
            unsigned hi = f2bfu(acc[2]) | (f2bfu(acc[3]) << 16);
            uint2 od = make_uint2(lo, hi);
            *reinterpret_cast<uint2*>(reinterpret_cast<char*>(P) +
                (size_t)(h * HW + pix) * 32 + g4 * 8) = od;
        }
    }
}

__device__ __forceinline__ void off_mfma(
    const float* __restrict__ query, const float* __restrict__ W_off,
    const float* __restrict__ b_off, float* __restrict__ offv, int qblk)
{
    const int tid = threadIdx.x;
    const int wave = tid >> 6, lane = tid & 63;
    const int col = lane & 15, g4 = lane >> 4;
    const int q = qblk * 64 + wave * 16 + col;

    bf16x8 bfrag[4];
    #pragma unroll
    for (int kk = 0; kk < 4; ++kk) {
        const float* qp = query + (size_t)q * 128 + kk * 32 + g4 * 8;
        bfrag[kk] = cvt8(*reinterpret_cast<const float4*>(qp),
                         *reinterpret_cast<const float4*>(qp + 4));
    }
    #pragma unroll
    for (int mt = 0; mt < 12; ++mt) {
        bf16x8 afrag[4];
        #pragma unroll
        for (int kk = 0; kk < 4; ++kk) {
            const float* wp = W_off + (size_t)(mt * 16 + col) * 128 + kk * 32 + g4 * 8;
            afrag[kk] = cvt8(*reinterpret_cast<const float4*>(wp),
                             *reinterpret_cast<const float4*>(wp + 4));
        }
        f32x4 acc = {0.f, 0.f, 0.f, 0.f};
        #pragma unroll
        for (int kk = 0; kk < 4; ++kk)
            acc = __builtin_amdgcn_mfma_f32_16x16x32_bf16(afrag[kk], bfrag[kk], acc, 0, 0, 0);
        float4 bias = *reinterpret_cast<const float4*>(b_off + mt * 16 + g4 * 4);
        float4 o = make_float4(acc[0] + bias.x, acc[1] + bias.y,
                               acc[2] + bias.z, acc[3] + bias.w);
        *reinterpret_cast<float4*>(offv + (size_t)q * 192 + mt * 16 + g4 * 4) = o;
    }
}

__global__ __launch_bounds__(256) void prep3_kernel(
    const float* __restrict__ feat0, const float* __restrict__ feat1,
    const float* __restrict__ feat2,
    const float* __restrict__ Wk0, const float* __restrict__ Wk1,
    const float* __restrict__ Wk2,
    __hip_bfloat16* __restrict__ P0, __hip_bfloat16* __restrict__ P1,
    __hip_bfloat16* __restrict__ P2,
    const float* __restrict__ query, const float* __restrict__ W_off,
    const float* __restrict__ b_off, float* __restrict__ offv)
{
    __shared__ __align__(16) unsigned short lds[128 * 128];  // 32 KB
    int b = blockIdx.x;
    if (b < 128)      proj_mfma<128>(lds, feat0, Wk0, P0, 16384, b);
    else if (b < 160) proj_mfma<128>(lds, feat1, Wk1, P1, 4096, b - 128);
    else if (b < 168) proj_mfma<64>(lds, feat2, Wk2, P2, 1024, b - 160);
    else              off_mfma(query, W_off, b_off, offv, b - 168);
}

// ===========================================================================
// attn6: one 128-thread block per query. 4 lanes per sample (quad = channel
// quad); geometry computed redundantly per quad-group in REGISTERS (no LDS
// staging, one fewer barrier). offv/ref loaded as float2 (quad-broadcast),
// then 12 corner uint2 loads batched. Corner-sum in-lane, logit via
// shfl_xor(1,2). Phase 2: softmax + combine.
// P layout: per-head [h][pix][16ch] bf16 (32 B/pixel).
// ===========================================================================
__global__ __launch_bounds__(128) void attn6_kernel(
    const float* __restrict__ query, const float* __restrict__ ref,
    const float* __restrict__ offv,
    const __hip_bfloat16* __restrict__ P0, const __hip_bfloat16* __restrict__ P1,
    const __hip_bfloat16* __restrict__ P2,
    const float* __restrict__ bk0, const float* __restrict__ bk1,
    const float* __restrict__ bk2,
    float* __restrict__ hout)
{
    __shared__ __align__(16) float q_sh[128];
    __shared__ __align__(16) float bias_sh[3][128];
    __shared__ float logit_sh[96];
    __shared__ __align__(16) float k_sh[96 * 20];   // stride 20: 16B-aligned, conflict-safe
    const int q = blockIdx.x;
    const int tid = threadIdx.x;
    q_sh[tid] = query[q * 128 + tid];
    bias_sh[0][tid] = bk0[tid];
    bias_sh[1][tid] = bk1[tid];
    bias_sh[2][tid] = bk2[tid];
    __syncthreads();

    const int grp = tid >> 2;   // 0..31 sample slot
    const int quad = tid & 3;   // channel quad

    // ---- per-sample geometry in registers (3 samples per lane) ----
    int hA[3], lA[3];
    float2 offr[3], refr[3];
    #pragma unroll
    for (int it = 0; it < 3; ++it) {
        int s = it * 32 + grp;
        int h = (s * 171) >> 11;      // s/12 for s<96
        int lp = s - h * 12;
        int l = lp >> 2;
        hA[it] = h; lA[it] = l;
        offr[it] = *reinterpret_cast<const float2*>(offv + q * 192 + 2 * s);
        refr[it] = *reinterpret_cast<const float2*>(ref + q * 6 + 2 * l);
    }

    uint2 raw[3][4];
    float4 wv[3];
    #pragma unroll
    for (int it = 0; it < 3; ++it) {
        int h = hA[it], l = lA[it];
        int W = 128 >> l;
        float x = fmaf(refr[it].x, (float)W, offr[it].x) - 0.5f;
        float y = fmaf(refr[it].y, (float)W, offr[it].y) - 0.5f;
        float x0f = floorf(x), y0f = floorf(y);
        float wx = x - x0f, wy = y - y0f;
        int x0 = (int)x0f, y0 = (int)y0f;
        int x1 = x0 + 1, y1 = y0 + 1;
        float mx0 = (x0 >= 0 && x0 < W) ? 1.f : 0.f;
        float mx1 = (x1 >= 0 && x1 < W) ? 1.f : 0.f;
        float my0 = (y0 >= 0 && y0 < W) ? 1.f : 0.f;
        float my1 = (y1 >= 0 && y1 < W) ? 1.f : 0.f;
        int xc0 = min(max(x0, 0), W - 1), xc1 = min(max(x1, 0), W - 1);
        int yc0 = min(max(y0, 0), W - 1), yc1 = min(max(y1, 0), W - 1);
        wv[it].x = (1.f - wx) * (1.f - wy) * mx0 * my0;
        wv[it].y = wx * (1.f - wy) * mx1 * my0;
        wv[it].z = (1.f - wx) * wy * mx0 * my1;
        wv[it].w = wx * wy * mx1 * my1;
        unsigned pb = (unsigned)(h * W * W) * 32u + (unsigned)quad * 8u;
        const char* base = (l == 0) ? (const char*)P0 :
                           (l == 1) ? (const char*)P1 : (const char*)P2;
        raw[it][0] = *reinterpret_cast<const uint2*>(base + pb + (unsigned)(yc0 * W + xc0) * 32u);
        raw[it][1] = *reinterpret_cast<const uint2*>(base + pb + (unsigned)(yc0 * W + xc1) * 32u);
        raw[it][2] = *reinterpret_cast<const uint2*>(base + pb + (unsigned)(yc1 * W + xc0) * 32u);
        raw[it][3] = *reinterpret_cast<const uint2*>(base + pb + (unsigned)(yc1 * W + xc1) * 32u);
    }

    // ---- process: bilinear in-reg, bias, logit, stash k ----
    #pragma unroll
    for (int it = 0; it < 3; ++it) {
        int s = it * 32 + grp;
        int h = hA[it], l = lA[it];
        float k0 = 0.f, k1 = 0.f, k2 = 0.f, k3 = 0.f;
        float wc[4] = {wv[it].x, wv[it].y, wv[it].z, wv[it].w};
        #pragma unroll
        for (int cnr = 0; cnr < 4; ++cnr) {
            unsigned a = raw[it][cnr].x, b2 = raw[it][cnr].y;
            float w = wc[cnr];
            k0 = fmaf(w, __uint_as_float(a << 16), k0);
            k1 = fmaf(w, __uint_as_float(a & 0xffff0000u), k1);
            k2 = fmaf(w, __uint_as_float(b2 << 16), k2);
            k3 = fmaf(w, __uint_as_float(b2 & 0xffff0000u), k3);
        }
        int co = h * 16 + quad * 4;
        float4 bias = *reinterpret_cast<const float4*>(&bias_sh[l][co]);
        k0 += bias.x; k1 += bias.y; k2 += bias.z; k3 += bias.w;
        float4 qv = *reinterpret_cast<const float4*>(&q_sh[co]);
        float lg = k0 * qv.x;
        lg = fmaf(k1, qv.y, lg);
        lg = fmaf(k2, qv.z, lg);
        lg = fmaf(k3, qv.w, lg);
        lg += __shfl_xor(lg, 1);
        lg += __shfl_xor(lg, 2);
        *reinterpret_cast<float4*>(&k_sh[s * 20 + quad * 4]) = make_float4(k0, k1, k2, k3);
        if (quad == 0) logit_sh[s] = lg;
    }
    __syncthreads();

    // ---- softmax + combine ----
    int h2 = tid >> 4, dd = tid & 15;
    float m = -1e30f;
    #pragma unroll
    for (int j = 0; j < 12; ++j) m = fmaxf(m, logit_sh[h2 * 12 + j]);
    float ssum = 0.f, o = 0.f;
    #pragma unroll
    for (int j = 0; j < 12; ++j) {
        float e = __expf(0.25f * (logit_sh[h2 * 12 + j] - m));
        ssum += e;
        o = fmaf(e, k_sh[(h2 * 12 + j) * 20 + dd], o);
    }
    hout[q * 128 + tid] = o / ssum;
}

// ===========================================================================
// output projection. Tile 64 rows (half) x 64 queries, K=128.
// ===========================================================================
__global__ __launch_bounds__(256) void outp2_kernel(
    const float* __restrict__ hin, const float* __restrict__ W_out,
    const float* __restrict__ b_out, float* __restrict__ out)
{
    __shared__ __align__(16) float w_sh[64 * 128];
    __shared__ __align__(16) float q_sh[64 * 128];
    int b = blockIdx.x;
    int qblk = b >> 1;
    int half = b & 1;
    int rbase = half * 64;
    int q0 = qblk * 64;
    int tid = threadIdx.x;

    for (int idx = tid; idx < 64 * 32; idx += 256) {
        int rl = idx >> 5;
        int ci4 = idx & 31;
        float4 v = *reinterpret_cast<const float4*>(&W_out[(rbase + rl) * 128 + ci4 * 4]);
        *reinterpret_cast<float4*>(&w_sh[rl * 128 + ((ci4 ^ (rl & 31)) << 2)]) = v;
    }
    for (int idx = tid; idx < 64 * 32; idx += 256) {
        int qq = idx >> 5;
        int ci4 = idx & 31;
        *reinterpret_cast<float4*>(&q_sh[qq * 128 + ci4 * 4]) =
            *reinterpret_cast<const float4*>(&hin[(q0 + qq) * 128 + ci4 * 4]);
    }
    __syncthreads();

    int c0 = tid & 31;
    int qg = tid >> 5;
    float acc[2][8];
    #pragma unroll
    for (int k = 0; k < 2; ++k)
        #pragma unroll
        for (int j = 0; j < 8; ++j) acc[k][j] = 0.f;

    #pragma unroll 4
    for (int ci4 = 0; ci4 < 32; ++ci4) {
        float4 A0 = *reinterpret_cast<const float4*>(&w_sh[c0 * 128 + ((ci4 ^ c0) << 2)]);
        float4 A1 = *reinterpret_cast<const float4*>(&w_sh[(c0 + 32) * 128 + ((ci4 ^ c0) << 2)]);
        #pragma unroll
        for (int j = 0; j < 8; ++j) {
            float4 B = *reinterpret_cast<const float4*>(&q_sh[(qg * 8 + j) * 128 + ci4 * 4]);
            acc[0][j] = fmaf(A0.x, B.x, acc[0][j]);
            acc[0][j] = fmaf(A0.y, B.y, acc[0][j]);
            acc[0][j] = fmaf(A0.z, B.z, acc[0][j]);
            acc[0][j] = fmaf(A0.w, B.w, acc[0][j]);
            acc[1][j] = fmaf(A1.x, B.x, acc[1][j]);
            acc[1][j] = fmaf(A1.y, B.y, acc[1][j]);
            acc[1][j] = fmaf(A1.z, B.z, acc[1][j]);
            acc[1][j] = fmaf(A1.w, B.w, acc[1][j]);
        }
    }
    #pragma unroll
    for (int k = 0; k < 2; ++k) {
        int r = rbase + c0 + 32 * k;
        float bias = b_out[r];
        #pragma unroll
        for (int j = 0; j < 8; ++j)
            out[(q0 + qg * 8 + j) * 128 + r] = acc[k][j] + bias;
    }
}

// ===========================================================================
extern "C" void kernel_launch(void* const* d_in, const int* in_sizes, int n_in,
                              void* d_out, int out_size, void* d_ws, size_t ws_size,
                              hipStream_t stream) {
    const float* query = (const float*)d_in[0];
    const float* ref   = (const float*)d_in[1];
    const float* feat0 = (const float*)d_in[2];
    const float* feat1 = (const float*)d_in[3];
    const float* feat2 = (const float*)d_in[4];
    const float* W_off = (const float*)d_in[6];
    const float* b_off = (const float*)d_in[7];
    const float* Wk0   = (const float*)d_in[8];
    const float* bk0   = (const float*)d_in[9];
    const float* Wk1   = (const float*)d_in[10];
    const float* bk1   = (const float*)d_in[11];
    const float* Wk2   = (const float*)d_in[12];
    const float* bk2   = (const float*)d_in[13];
    const float* W_out = (const float*)d_in[14];
    const float* b_out = (const float*)d_in[15];
    float* out = (float*)d_out;

    __hip_bfloat16* P0 = (__hip_bfloat16*)d_ws;     // [8][16384][16] bf16
    __hip_bfloat16* P1 = P0 + 8 * 16384 * 16;       // [8][4096][16]
    __hip_bfloat16* P2 = P1 + 8 * 4096 * 16;        // [8][1024][16]
    float* offv = (float*)(P2 + 8 * 1024 * 16);     // [6400][192] f32
    float* hout = offv + 6400 * 192;                // [6400][128] f32

    hipLaunchKernelGGL(prep3_kernel, dim3(268), dim3(256), 0, stream,
                       feat0, feat1, feat2, Wk0, Wk1, Wk2, P0, P1, P2,
                       query, W_off, b_off, offv);
    hipLaunchKernelGGL(attn6_kernel, dim3(6400), dim3(128), 0, stream,
                       query, ref, offv, P0, P1, P2, bk0, bk1, bk2, hout);
    hipLaunchKernelGGL(outp2_kernel, dim3(200), dim3(256), 0, stream,
                       hout, W_out, b_out, out);
}